// Round 10
// baseline (43.869 us; speedup 1.0000x reference)
//
#include <hip/hip_runtime.h>
#include <math.h>

#define TPB     256
#define COLS2   32             // float2-columns per block (= 64 scalar cols)
#define SEGS    8              // output segments per block (TPB/COLS2)
#define SEGLEN  8              // t's per thread
#define TSPAN   (SEGS * SEGLEN)    // 64 t's per block
#define HSEGLEN 13             // halo rows scanned per thread
#define HALO    (SEGS * HSEGLEN)   // 104 >= reference max nw (100)

// ---------------------------------------------------------------------------
// GARCH sigma, untruncated-IIR formulation (see R5-R8 notes).
//   a[t+1] = beta*a[t] + x2[t],  sigma[t] = sqrt(w0 + alpha*a[t])
// Seed truncated at >=104 taps; vs reference's nw<=100-tap FIR the error is
// the beta^{>=100} tail: measured ~4e-3 vs threshold 1.6e-2.
//
// R10 delta vs R9: restore concurrency. R9's float2 at TSPAN=128 halved the
// grid (2048 blocks = 1 residency round -> read & write bursts serialize,
// the R6 failure). Here SEGLEN=8 / TSPAN=64 -> 4096 blocks / 2 rounds (same
// thread count & overlap structure as the 26us R8) while keeping float2's
// 8B/lane coalescing: 21+8 vmem instrs/thread vs R8's 32+16.
// ---------------------------------------------------------------------------

__device__ __forceinline__ float fast_sigmoid(float x) {
    const float LOG2E = 1.4426950408889634f;
    const float e = __builtin_amdgcn_exp2f(-x * LOG2E);
    return __builtin_amdgcn_rcpf(1.0f + e);
}

__global__ __launch_bounds__(TPB) void garch_sigma_kernel(
    const float2* __restrict__ xp,
    const float2* __restrict__ ar2,
    const float2* __restrict__ br2,
    const float2* __restrict__ or2,
    float2*       __restrict__ outp,
    int T, int N2) {

    __shared__ float2 QsH[SEGS][COLS2];   // halo partials (13 rows each)
    __shared__ float2 QsO[SEGS][COLS2];   // own-segment partials (8 rows each)

    const int tid = threadIdx.x;
    const int c2  = tid & (COLS2 - 1);
    const int k   = tid >> 5;                       // segment 0..7
    const int n2  = blockIdx.x * COLS2 + c2;
    const int t0  = blockIdx.y * TSPAN;

    const int  nc     = (n2 < N2) ? n2 : (N2 - 1); // clamp for ragged N
    const bool col_ok = (n2 < N2);

    const float2 arv = ar2[nc];
    const float2 brv = br2[nc];
    const float2 orv = or2[nc];
    const float ax = fast_sigmoid(arv.x), ay = fast_sigmoid(arv.y);
    const float bx = fast_sigmoid(brv.x) * 0.9999f;
    const float by = fast_sigmoid(brv.y) * 0.9999f;
    const float ox = fast_sigmoid(orv.x), oy = fast_sigmoid(orv.y);
    const float w0x = ox * ox * __builtin_amdgcn_rcpf(1.0f - bx);
    const float w0y = oy * oy * __builtin_amdgcn_rcpf(1.0f - by);

    // ---------------- phase 1: issue ALL loads up front -------------------
    const int h0 = t0 - HALO + k * HSEGLEN;         // halo segment start
    const int g0 = t0 + k * SEGLEN;                 // own segment start

    float2 h[HSEGLEN];
    if (h0 >= 0) {                                  // fully valid (common case)
        const int base = h0 * N2 + nc;
        #pragma unroll
        for (int i = 0; i < HSEGLEN; ++i)
            h[i] = xp[base + i * N2];
    } else {                                        // first y-blocks: straddle t=0
        #pragma unroll
        for (int i = 0; i < HSEGLEN; ++i) {
            if (h0 + i >= 0) h[i] = xp[(h0 + i) * N2 + nc];
            else             h[i] = make_float2(0.f, 0.f);
        }
    }

    float2 p[SEGLEN];
    {
        const int base = g0 * N2 + nc;
        if (t0 + TSPAN <= T) {                      // full tile: no guards
            #pragma unroll
            for (int i = 0; i < SEGLEN; ++i)
                p[i] = xp[base + i * N2];
        } else {
            #pragma unroll
            for (int i = 0; i < SEGLEN; ++i) {
                if (g0 + i < T) p[i] = xp[base + i * N2];
                else            p[i] = make_float2(0.f, 0.f);
            }
        }
    }

    // ---------------- scans -> partials ----------------
    {
        float qx = 0.f, qy = 0.f;
        #pragma unroll
        for (int i = 0; i < HSEGLEN; ++i) {
            qx = fmaf(bx, qx, h[i].x * h[i].x);
            qy = fmaf(by, qy, h[i].y * h[i].y);
        }
        QsH[k][c2] = make_float2(qx, qy);
    }
    {
        float qx = 0.f, qy = 0.f;
        #pragma unroll
        for (int i = 0; i < SEGLEN; ++i) {
            const float sx = p[i].x * p[i].x;
            const float sy = p[i].y * p[i].y;
            p[i] = make_float2(sx, sy);
            qx = fmaf(bx, qx, sx);
            qy = fmaf(by, qy, sy);
        }
        QsO[k][c2] = make_float2(qx, qy);
    }

    __syncthreads();

    // ------------- phase 2: seed via mixed-radix Horner (b13, b8) ---------
    const float bx2 = bx * bx,   by2 = by * by;
    const float bx4 = bx2 * bx2, by4 = by2 * by2;
    const float bx8 = bx4 * bx4, by8 = by4 * by4;
    const float b13x = bx8 * bx4 * bx, b13y = by8 * by4 * by;

    float a_x = 0.f, a_y = 0.f;
    #pragma unroll
    for (int u = 0; u < SEGS; ++u) {                // halo, oldest first
        const float2 q = QsH[u][c2];
        a_x = fmaf(a_x, b13x, q.x);
        a_y = fmaf(a_y, b13y, q.y);
    }
    for (int u = 0; u < k; ++u) {                   // own segments before g0
        const float2 q = QsO[u][c2];
        a_x = fmaf(a_x, bx8, q.x);
        a_y = fmaf(a_y, by8, q.y);
    }

    // ---------------- emit 8 float2 outputs from registers ----------------
    if (col_ok) {
        float2* op = outp + (g0 * N2 + nc);
        if (t0 + TSPAN <= T) {
            #pragma unroll
            for (int i = 0; i < SEGLEN; ++i) {
                float2 sg;
                sg.x = __builtin_amdgcn_sqrtf(fmaf(ax, a_x, w0x));
                sg.y = __builtin_amdgcn_sqrtf(fmaf(ay, a_y, w0y));
                union { float2 f2; double d; } u2; u2.f2 = sg;
                __builtin_nontemporal_store(u2.d, (double*)(op + i * N2));
                a_x = fmaf(bx, a_x, p[i].x);
                a_y = fmaf(by, a_y, p[i].y);
            }
        } else {
            #pragma unroll
            for (int i = 0; i < SEGLEN; ++i) {
                float2 sg;
                sg.x = __builtin_amdgcn_sqrtf(fmaf(ax, a_x, w0x));
                sg.y = __builtin_amdgcn_sqrtf(fmaf(ay, a_y, w0y));
                if (g0 + i < T) {
                    union { float2 f2; double d; } u2; u2.f2 = sg;
                    __builtin_nontemporal_store(u2.d, (double*)(op + i * N2));
                }
                a_x = fmaf(bx, a_x, p[i].x);
                a_y = fmaf(by, a_y, p[i].y);
            }
        }
    }
}

// ---------------------------------------------------------------------------
extern "C" void kernel_launch(void* const* d_in, const int* in_sizes, int n_in,
                              void* d_out, int out_size, void* d_ws, size_t ws_size,
                              hipStream_t stream) {
    const float* x   = (const float*)d_in[0];
    const float* ar  = (const float*)d_in[1];
    const float* br  = (const float*)d_in[2];
    const float* orw = (const float*)d_in[3];
    float* out = (float*)d_out;

    const int N  = in_sizes[1];         // alpha_raw is [1, N]
    const int T  = in_sizes[0] / N;     // x is [T, N]
    const int N2 = N >> 1;

    dim3 grid((N2 + COLS2 - 1) / COLS2, (T + TSPAN - 1) / TSPAN);
    hipLaunchKernelGGL(garch_sigma_kernel, grid, dim3(TPB), 0, stream,
                       (const float2*)x, (const float2*)ar, (const float2*)br,
                       (const float2*)orw, (float2*)out, T, N2);
}

// Round 11
// 26.771 us; speedup vs baseline: 1.6387x; 1.6387x over previous
//
#include <hip/hip_runtime.h>
#include <math.h>

#define TPB     256
#define COLS    32             // scalar columns per block
#define SEGS    8              // output segments per block (TPB/COLS)
#define SEGLEN  8              // t's per thread
#define TSPAN   (SEGS * SEGLEN)    // 64 t's per block
#define HSEGLEN 13             // halo rows scanned per thread
#define HALO    (SEGS * HSEGLEN)   // 104 >= reference max nw (100)

// ---------------------------------------------------------------------------
// GARCH sigma, untruncated-IIR formulation (see R5-R8 notes).
//   a[t+1] = beta*a[t] + x2[t],  sigma[t] = sqrt(w0 + alpha*a[t])
// Seed truncated at >=104 taps; vs reference's nw<=100-tap FIR the error is
// the beta^{>=100} tail: measured ~4e-3 vs threshold 1.6e-2.
//
// R11 delta vs R8 (best, 26.1us): 4 residency rounds instead of 2.
// TSPAN 128->64 => grid 8192 blocks (8 resident/CU, 4 rounds): finer
// read/write pipelining across rounds. Halo 128->104 rows (13/thread,
// mixed-radix seed b13/b8) to limit the added halo amplification.
// Scalar loads/stores kept: float2 variants (R9/R10) regressed hard in the
// timed (graph-replay) regime despite identical profiled duration.
// ---------------------------------------------------------------------------

__device__ __forceinline__ float fast_sigmoid(float x) {
    const float LOG2E = 1.4426950408889634f;
    const float e = __builtin_amdgcn_exp2f(-x * LOG2E);
    return __builtin_amdgcn_rcpf(1.0f + e);
}

__global__ __launch_bounds__(TPB) void garch_sigma_kernel(
    const float* __restrict__ x,
    const float* __restrict__ alpha_raw,
    const float* __restrict__ beta_raw,
    const float* __restrict__ omega_raw,
    float*       __restrict__ out,
    int T, int N) {

    __shared__ float QsH[SEGS][COLS];   // halo partials (13 rows each)
    __shared__ float QsO[SEGS][COLS];   // own-segment partials (8 rows each)

    const int tid = threadIdx.x;
    const int col = tid & (COLS - 1);
    const int k   = tid >> 5;                       // segment 0..7
    const int n   = blockIdx.x * COLS + col;
    const int t0  = blockIdx.y * TSPAN;

    const int  nc     = (n < N) ? n : (N - 1);      // clamp for ragged N
    const bool col_ok = (n < N);

    const float alpha = fast_sigmoid(alpha_raw[nc]);
    const float beta  = fast_sigmoid(beta_raw[nc]) * 0.9999f;
    const float om    = fast_sigmoid(omega_raw[nc]);
    const float w0    = om * om * __builtin_amdgcn_rcpf(1.0f - beta);

    // ---------------- phase 1: issue ALL loads up front -------------------
    const int h0 = t0 - HALO + k * HSEGLEN;         // halo segment start
    const int g0 = t0 + k * SEGLEN;                 // own segment start

    float h[HSEGLEN];
    if (h0 >= 0) {                                  // fully valid (common case)
        const int base = h0 * N + nc;
        #pragma unroll
        for (int i = 0; i < HSEGLEN; ++i)
            h[i] = x[base + i * N];
    } else {                                        // first y-blocks: straddle t=0
        #pragma unroll
        for (int i = 0; i < HSEGLEN; ++i)
            h[i] = (h0 + i >= 0) ? x[(h0 + i) * N + nc] : 0.f;
    }

    float p[SEGLEN];
    {
        const int base = g0 * N + nc;
        if (t0 + TSPAN <= T) {                      // full tile: no guards
            #pragma unroll
            for (int i = 0; i < SEGLEN; ++i)
                p[i] = x[base + i * N];
        } else {
            #pragma unroll
            for (int i = 0; i < SEGLEN; ++i)
                p[i] = (g0 + i < T) ? x[base + i * N] : 0.f;
        }
    }

    // ---------------- scans -> partials ----------------
    {
        float q = 0.f;
        #pragma unroll
        for (int i = 0; i < HSEGLEN; ++i)
            q = fmaf(beta, q, h[i] * h[i]);
        QsH[k][col] = q;
    }
    {
        float q = 0.f;
        #pragma unroll
        for (int i = 0; i < SEGLEN; ++i) {
            const float s = p[i] * p[i];
            p[i] = s;
            q = fmaf(beta, q, s);
        }
        QsO[k][col] = q;
    }

    __syncthreads();

    // ------------- phase 2: seed via mixed-radix Horner (b13 halo, b8 own)
    const float b2  = beta * beta;
    const float b4  = b2 * b2;
    const float b8  = b4 * b4;
    const float b13 = b8 * b4 * beta;

    float a = 0.f;
    #pragma unroll
    for (int u = 0; u < SEGS; ++u)                  // halo, oldest first
        a = fmaf(a, b13, QsH[u][col]);
    for (int u = 0; u < k; ++u)                     // own segments before g0
        a = fmaf(a, b8, QsO[u][col]);

    // ---------------- emit 8 outputs from registers -----------------------
    if (col_ok) {
        float* op = out + (g0 * N + nc);
        if (t0 + TSPAN <= T) {
            #pragma unroll
            for (int i = 0; i < SEGLEN; ++i) {
                const float sg = __builtin_amdgcn_sqrtf(fmaf(alpha, a, w0));
                __builtin_nontemporal_store(sg, op + i * N);
                a = fmaf(beta, a, p[i]);
            }
        } else {
            #pragma unroll
            for (int i = 0; i < SEGLEN; ++i) {
                const float sg = __builtin_amdgcn_sqrtf(fmaf(alpha, a, w0));
                if (g0 + i < T)
                    __builtin_nontemporal_store(sg, op + i * N);
                a = fmaf(beta, a, p[i]);
            }
        }
    }
}

// ---------------------------------------------------------------------------
extern "C" void kernel_launch(void* const* d_in, const int* in_sizes, int n_in,
                              void* d_out, int out_size, void* d_ws, size_t ws_size,
                              hipStream_t stream) {
    const float* x   = (const float*)d_in[0];
    const float* ar  = (const float*)d_in[1];
    const float* br  = (const float*)d_in[2];
    const float* orw = (const float*)d_in[3];
    float* out = (float*)d_out;

    const int N = in_sizes[1];          // alpha_raw is [1, N]
    const int T = in_sizes[0] / N;      // x is [T, N]

    dim3 grid((N + COLS - 1) / COLS, (T + TSPAN - 1) / TSPAN);
    hipLaunchKernelGGL(garch_sigma_kernel, grid, dim3(TPB), 0, stream,
                       x, ar, br, orw, out, T, N);
}

// Round 12
// 26.557 us; speedup vs baseline: 1.6519x; 1.0080x over previous
//
#include <hip/hip_runtime.h>
#include <math.h>

#define TPB     256
#define COLS    32             // scalar columns per block
#define SEGS    8              // output segments per block (TPB/COLS)
#define SEGLEN  16             // t's per thread
#define TSPAN   (SEGS * SEGLEN)   // 128 t's per block
#define HSEGLEN 16             // halo rows scanned per thread
#define HALO    (SEGS * HSEGLEN)  // 128 >= max nw (100)

// ---------------------------------------------------------------------------
// GARCH sigma, untruncated-IIR formulation.
//   a[t+1] = beta*a[t] + x2[t],  sigma[t] = sqrt(w0 + alpha*a[t])
// vs the reference's nw-tap truncated FIR the difference is the beta^j tail
// (j >= nw): measured absmax 3.9e-3 vs threshold 1.6e-2.
//
// R12 delta vs R8 (best, 26.1us): ONE change — nontemporal stores -> plain
// stores. NT forced a full 64MB HBM write drain per replay (WRITE_SIZE=64MB
// on every profiled dispatch). The timed regime replays onto the same d_out:
// steady-state working set = x(64MB) + out(64MB) = 128MB < 256MB Infinity
// Cache (write-back, memory-side). Plain stores let dirty out-lines be
// rewritten in-cache across replays instead of draining to HBM each time.
// ---------------------------------------------------------------------------

__device__ __forceinline__ float fast_sigmoid(float x) {
    const float LOG2E = 1.4426950408889634f;
    const float e = __builtin_amdgcn_exp2f(-x * LOG2E);
    return __builtin_amdgcn_rcpf(1.0f + e);
}

__global__ __launch_bounds__(TPB) void garch_sigma_kernel(
    const float* __restrict__ x,
    const float* __restrict__ alpha_raw,
    const float* __restrict__ beta_raw,
    const float* __restrict__ omega_raw,
    float*       __restrict__ out,
    int T, int N) {

    __shared__ float QsH[SEGS][COLS];   // halo partials (16 rows each)
    __shared__ float QsO[SEGS][COLS];   // own-segment partials (16 rows each)

    const int tid = threadIdx.x;
    const int col = tid & (COLS - 1);
    const int k   = tid >> 5;                       // segment 0..7
    const int n   = blockIdx.x * COLS + col;
    const int t0  = blockIdx.y * TSPAN;

    const int  nc     = (n < N) ? n : (N - 1);      // clamp for ragged N
    const bool col_ok = (n < N);

    const float alpha = fast_sigmoid(alpha_raw[nc]);
    const float beta  = fast_sigmoid(beta_raw[nc]) * 0.9999f;
    const float om    = fast_sigmoid(omega_raw[nc]);
    const float w0    = om * om * __builtin_amdgcn_rcpf(1.0f - beta);

    // ---------------- phase 1: issue ALL loads up front -------------------
    const int h0 = t0 - HALO + k * HSEGLEN;         // halo segment start
    const int g0 = t0 + k * SEGLEN;                 // own segment start

    float h[HSEGLEN];
    const bool have_halo = (h0 >= 0);               // halo seg all-valid or all-zero
    if (have_halo) {
        const int base = h0 * N + nc;               // 32-bit offsets
        #pragma unroll
        for (int i = 0; i < HSEGLEN; ++i)
            h[i] = x[base + i * N];
    }

    float p[SEGLEN];
    {
        const int base = g0 * N + nc;
        if (t0 + TSPAN <= T) {                      // full tile: no guards
            #pragma unroll
            for (int i = 0; i < SEGLEN; ++i)
                p[i] = x[base + i * N];
        } else {
            #pragma unroll
            for (int i = 0; i < SEGLEN; ++i)
                p[i] = (g0 + i < T) ? x[base + i * N] : 0.f;
        }
    }

    // ---------------- scans -> partials ----------------
    {
        float q = 0.f;
        if (have_halo) {
            #pragma unroll
            for (int i = 0; i < HSEGLEN; ++i)
                q = fmaf(beta, q, h[i] * h[i]);
        }
        QsH[k][col] = q;
    }
    {
        float q = 0.f;
        #pragma unroll
        for (int i = 0; i < SEGLEN; ++i) {
            const float s = p[i] * p[i];
            p[i] = s;
            q = fmaf(beta, q, s);
        }
        QsO[k][col] = q;
    }

    __syncthreads();

    // ---------------- phase 2: seed via Horner in beta^16 -----------------
    const float b2  = beta * beta;
    const float b4  = b2 * b2;
    const float b8  = b4 * b4;
    const float b16 = b8 * b8;

    float a = 0.f;
    #pragma unroll
    for (int u = 0; u < SEGS; ++u)                  // halo, oldest first
        a = fmaf(a, b16, QsH[u][col]);
    for (int u = 0; u < k; ++u)                     // own segments before g0
        a = fmaf(a, b16, QsO[u][col]);

    // ---------------- emit 16 outputs from registers ----------------------
    if (col_ok) {
        float* op = out + (g0 * N + nc);            // 32-bit offset
        if (t0 + TSPAN <= T) {
            #pragma unroll
            for (int i = 0; i < SEGLEN; ++i) {
                const float sg = __builtin_amdgcn_sqrtf(fmaf(alpha, a, w0));
                op[i * N] = sg;                     // cached store (L2/L3 absorb)
                a = fmaf(beta, a, p[i]);
            }
        } else {
            #pragma unroll
            for (int i = 0; i < SEGLEN; ++i) {
                const float sg = __builtin_amdgcn_sqrtf(fmaf(alpha, a, w0));
                if (g0 + i < T)
                    op[i * N] = sg;
                a = fmaf(beta, a, p[i]);
            }
        }
    }
}

// ---------------------------------------------------------------------------
extern "C" void kernel_launch(void* const* d_in, const int* in_sizes, int n_in,
                              void* d_out, int out_size, void* d_ws, size_t ws_size,
                              hipStream_t stream) {
    const float* x   = (const float*)d_in[0];
    const float* ar  = (const float*)d_in[1];
    const float* br  = (const float*)d_in[2];
    const float* orw = (const float*)d_in[3];
    float* out = (float*)d_out;

    const int N = in_sizes[1];          // alpha_raw is [1, N]
    const int T = in_sizes[0] / N;      // x is [T, N]

    dim3 grid((N + COLS - 1) / COLS, (T + TSPAN - 1) / TSPAN);
    hipLaunchKernelGGL(garch_sigma_kernel, grid, dim3(TPB), 0, stream,
                       x, ar, br, orw, out, T, N);
}